// Round 12
// baseline (250.885 us; speedup 1.0000x reference)
//
#include <hip/hip_runtime.h>

// AdderNet 2D: out[n,f,h,w] = -sum_{c,kh,kw} |W[f,c,kh,kw] - xpad[n,c,h+kh,w+kw]|
// x: (16,64,14,14) fp32, W: (64,64,3,3) fp32, out: (16,64,14,14) fp32
//
// R12 DIAGNOSTIC: R11 body + __launch_bounds__(256, 1). R10/R11 showed the
// allocator picks ~64 VGPR on its own (8 waves/EU heuristic) and spills
// Wr/xr -> ~90 MB scratch HBM traffic per pass = the invariant ~29us wall
// (21us spill + 8us intercept). min_waves=1 explicitly licenses up to
// ~256 VGPRs (body needs ~100). REPS=24 keeps the kernel visible in the
// profile so VGPR_Count / FETCH_SIZE / VALUBusy verify or kill the theory.

#define N_ 16
#define C_ 64
#define F_ 64
#define P_ 196
#define REPS 24

__global__ __launch_bounds__(256, 1) void adder2d_kernel(
    const float* __restrict__ x, const float* __restrict__ w,
    float* __restrict__ out)
{
    // [c(16)][r(3)][col(16, zero-padded)] = 768 floats = 3 KB
    __shared__ __align__(16) float xs[16 * 48];
    __shared__ float part[4][64 * 15];   // stride 15 -> conflict-free

    const int tid = threadIdx.x;        // 0..255
    const int row = blockIdx.x;         // 0..13 output row
    const int n   = blockIdx.y;         // 0..15
    const int cs  = blockIdx.z;         // 0..3 channel slice (16 ch)
    const int f   = tid & 63;           // lane = filter
    const int wid = tid >> 6;           // wave 0..3 -> ch quad
    const int cbase = cs * 16 + wid * 4;

    // ---- stage 16ch x 3 rows x 16 cols (padded) into LDS: 3 stores/thr ----
    #pragma unroll
    for (int i = 0; i < 3; ++i) {
        const int idx = tid + 256 * i;          // 0..767
        const int c   = idx / 48;
        const int rem = idx - c * 48;
        const int r   = rem >> 4;               // 0..2
        const int col = rem & 15;               // 0..15
        const int ir  = row + r - 1;            // input row, -1..14
        float v = 0.f;
        if (col >= 1 && col <= 14 && ir >= 0 && ir <= 13)
            v = x[(n * C_ + cs * 16 + c) * P_ + ir * 14 + (col - 1)];
        xs[idx] = v;
    }

    // ---- W[f][cbase..cbase+3][0..8]: 36 floats, 9 dwordx4, loaded once ----
    float Wr[36];
    {
        const float4* wp = (const float4*)(w + f * (C_ * 9) + cbase * 9);
        #pragma unroll
        for (int i = 0; i < 9; ++i) {
            float4 t = wp[i];
            Wr[4 * i + 0] = t.x; Wr[4 * i + 1] = t.y;
            Wr[4 * i + 2] = t.z; Wr[4 * i + 3] = t.w;
        }
    }

    float acc[14];
    #pragma unroll
    for (int p = 0; p < 14; ++p) acc[p] = 0.f;

    __syncthreads();

    const float* xb = xs + (wid * 4) * 48;   // this wave's ch-quad base

    #pragma unroll 1
    for (int rep = 0; rep < REPS; ++rep) {
        asm volatile("" ::: "memory");   // forbid cross-rep LDS-read CSE
        #pragma unroll
        for (int cl = 0; cl < 4; ++cl) {
            #pragma unroll
            for (int kh = 0; kh < 3; ++kh) {
                const float4* rp = (const float4*)(xb + cl * 48 + kh * 16);
                float4 q0 = rp[0], q1 = rp[1], q2 = rp[2], q3 = rp[3];
                float xr[16] = {q0.x, q0.y, q0.z, q0.w,  q1.x, q1.y, q1.z, q1.w,
                                q2.x, q2.y, q2.z, q2.w,  q3.x, q3.y, q3.z, q3.w};
                #pragma unroll
                for (int kw = 0; kw < 3; ++kw) {
                    const float wv = Wr[cl * 9 + kh * 3 + kw];  // const index
                    #pragma unroll
                    for (int p = 0; p < 14; ++p)
                        acc[p] += fabsf(wv - xr[p + kw]);
                }
            }
        }
    }

    // ---- 4-wave partial reduce in LDS (scale out the reps) ----
    #pragma unroll
    for (int p = 0; p < 14; ++p)
        part[wid][f * 15 + p] = acc[p] * (1.0f / REPS);
    __syncthreads();

    // ---- 896 outputs this block; atomic add into zeroed d_out ----
    for (int o = tid; o < 896; o += 256) {
        const int ff = o / 14;
        const int px = o - ff * 14;
        const int a  = ff * 15 + px;
        float s = part[0][a] + part[1][a] + part[2][a] + part[3][a];
        atomicAdd(&out[(n * F_ + ff) * P_ + row * 14 + px], -s);
    }
}

extern "C" void kernel_launch(void* const* d_in, const int* in_sizes, int n_in,
                              void* d_out, int out_size, void* d_ws, size_t ws_size,
                              hipStream_t stream) {
    const float* x = (const float*)d_in[0];
    const float* w = (const float*)d_in[1];
    float* out = (float*)d_out;
    // d_out is re-poisoned 0xAA before every call -> zero it (graph-legal)
    hipMemsetAsync(out, 0, (size_t)out_size * sizeof(float), stream);
    dim3 grid(14, N_, 4);
    adder2d_kernel<<<grid, 256, 0, stream>>>(x, w, out);
}

// Round 13
// 71.022 us; speedup vs baseline: 3.5325x; 3.5325x over previous
//
#include <hip/hip_runtime.h>

// AdderNet 2D: out[n,f,h,w] = -sum_{c,kh,kw} |W[f,c,kh,kw] - xpad[n,c,h+kh,w+kw]|
// x: (16,64,14,14) fp32, W: (64,64,3,3) fp32, out: (16,64,14,14) fp32
//
// R13: self-contained blocks (kill the 20.6us intercept R12 measured:
// memset dispatch + 784K atomics + 2-dispatch overhead). Grid = (14 row,
// 16 n, 4 fg) = 896 blocks x 256 thr. lane = (c_sub x16 | f_local),
// wave = 16-ch group -> block covers ALL 64 ch for 16 f x 14 px ->
// direct stores. Body = R12's measured-good profile (VGPR 112, no spill
// under (256,1)): Wr[36] contiguous, acc[14], xr[16] via ds_read_b128.
// x tile ch-stride 60: c_sub bank offsets {0,16,0,16} -> 2-way = free.
// Channel reduce: shfl_xor(16,32) + part[4] in LDS.

#define N_ 16
#define C_ 64
#define F_ 64
#define P_ 196
#define CSTRIDE 60   // dwords per channel in xs (48 data + pad; 16B-aligned)

__global__ __launch_bounds__(256, 1) void adder2d_kernel(
    const float* __restrict__ x, const float* __restrict__ w,
    float* __restrict__ out)
{
    __shared__ __align__(16) float xs[C_ * CSTRIDE];   // 15,360 B
    __shared__ float part[4][16][15];                  //  3,840 B

    const int tid = threadIdx.x;        // 0..255
    const int row = blockIdx.x;         // 0..13 output row
    const int n   = blockIdx.y;         // 0..15
    const int fg  = blockIdx.z;         // 0..3 -> filters fg*16..fg*16+15

    // ---- stage 64ch x 3rows x 16cols (zero-padded) into xs: 12 st/thr ----
    #pragma unroll
    for (int i = 0; i < 12; ++i) {
        const int idx = tid + 256 * i;          // 0..3071
        const int c   = idx / 48;
        const int rem = idx - c * 48;
        const int r   = rem >> 4;               // 0..2
        const int col = rem & 15;               // 0..15 padded col
        const int ir  = row + r - 1;            // input row, -1..14
        float v = 0.f;
        if (col >= 1 && col <= 14 && ir >= 0 && ir <= 13)
            v = x[(n * C_ + c) * P_ + ir * 14 + (col - 1)];
        xs[c * CSTRIDE + r * 16 + col] = v;
    }

    const int f_local = tid & 15;              // 0..15
    const int c_sub   = (tid >> 4) & 3;        // 0..3
    const int wv      = tid >> 6;              // wave 0..3
    const int cb      = wv * 16 + c_sub * 4;   // lane's 4 channels: cb..cb+3

    // ---- W[fg*16+f_local][cb..cb+3][0..8]: 36 contiguous, 16B-aligned ----
    float Wr[36];
    {
        const float4* wp = (const float4*)(w + (fg * 16 + f_local) * (C_ * 9)
                                             + cb * 9);
        #pragma unroll
        for (int i = 0; i < 9; ++i) {
            float4 t = wp[i];
            Wr[4 * i + 0] = t.x; Wr[4 * i + 1] = t.y;
            Wr[4 * i + 2] = t.z; Wr[4 * i + 3] = t.w;
        }
    }

    float acc[14];
    #pragma unroll
    for (int p = 0; p < 14; ++p) acc[p] = 0.f;

    __syncthreads();

    // ---- hot loop: 4 ch x 3 kh x (4 ds_read_b128 + 84 VALU) ----
    const float* xb = xs + cb * CSTRIDE;
    #pragma unroll
    for (int cl = 0; cl < 4; ++cl) {
        #pragma unroll
        for (int kh = 0; kh < 3; ++kh) {
            const float4* rp = (const float4*)(xb + cl * CSTRIDE + kh * 16);
            float4 q0 = rp[0], q1 = rp[1], q2 = rp[2], q3 = rp[3];
            float xr[16] = {q0.x, q0.y, q0.z, q0.w,  q1.x, q1.y, q1.z, q1.w,
                            q2.x, q2.y, q2.z, q2.w,  q3.x, q3.y, q3.z, q3.w};
            #pragma unroll
            for (int kw = 0; kw < 3; ++kw) {
                const float wvv = Wr[cl * 9 + kh * 3 + kw];  // const index
                #pragma unroll
                for (int p = 0; p < 14; ++p)
                    acc[p] += fabsf(wvv - xr[p + kw]);
            }
        }
    }

    // ---- reduce over c_sub (lanes +-16, +-32) via shuffle-xor ----
    #pragma unroll
    for (int p = 0; p < 14; ++p) {
        acc[p] += __shfl_xor(acc[p], 16);
        acc[p] += __shfl_xor(acc[p], 32);
    }

    // ---- cross-wave: wave wv's lanes 0..15 hold its 16-ch sums ----
    if (c_sub == 0 && (tid & 15) == f_local) {   // lanes 0..15 of each wave
        #pragma unroll
        for (int p = 0; p < 14; ++p)
            part[wv][f_local][p] = acc[p];
    }
    __syncthreads();

    // ---- final 4-way sum + direct store: 224 outputs ----
    if (tid < 224) {
        const int f  = tid / 14;
        const int px = tid - f * 14;
        float s = part[0][f][px] + part[1][f][px]
                + part[2][f][px] + part[3][f][px];
        out[(n * F_ + fg * 16 + f) * P_ + row * 14 + px] = -s;
    }
}

extern "C" void kernel_launch(void* const* d_in, const int* in_sizes, int n_in,
                              void* d_out, int out_size, void* d_ws, size_t ws_size,
                              hipStream_t stream) {
    const float* x = (const float*)d_in[0];
    const float* w = (const float*)d_in[1];
    float* out = (float*)d_out;
    dim3 grid(14, N_, 4);
    adder2d_kernel<<<grid, 256, 0, stream>>>(x, w, out);
}